// Round 5
// baseline (750.574 us; speedup 1.0000x reference)
//
#include <hip/hip_runtime.h>
#include <math.h>

#define BLOCK 256
#define ROWS 4

typedef __attribute__((ext_vector_type(8))) short s16x8;
typedef __attribute__((ext_vector_type(4))) float f32x4;

// ---- LDS layout (dword offsets) ----
static constexpr int O_W1  = 0;      // bf16 [128][72]  -> 4608 dw
static constexpr int O_W2  = 4608;   // bf16 [128][136] -> 8704 dw
static constexpr int O_W3  = 13312;  // bf16 [16][136]  -> 1088 dw
static constexpr int O_INB = 14400;  // bf16 [16][72]   -> 576 dw
static constexpr int O_H1  = 14976;  // bf16 [16][136]  -> 1088 dw
static constexpr int O_H2  = 16064;  // bf16 [16][136]  -> 1088 dw
static constexpr int O_B1  = 17152;  // f32 [128]
static constexpr int O_B2  = 17280;  // f32 [128]
static constexpr int O_B3  = 17408;  // f32 [8]
static constexpr int O_SU  = 17416;  // f32 [4][256] = 1024 dw
static constexpr int O_YPM = 18440;  // f32 [4][40]  = 160 dw
static constexpr int O_UPM = 18600;  // f32 [4][12]  = 48 dw
static constexpr int O_XM  = 18648;  // f32 [4][8]   = 32 dw
static constexpr int LDSN  = 18680;  // 74720 bytes -> 2 blocks/CU

__device__ __forceinline__ unsigned short f2bf(float f) {  // fp32->bf16 RNE
  unsigned u = __float_as_uint(f);
  return (unsigned short)((u + 0x7fffu + ((u >> 16) & 1u)) >> 16);
}
__device__ __forceinline__ unsigned cvt_pk_bf16(float lo, float hi) {
  unsigned r;
  asm("v_cvt_pk_bf16_f32 %0, %1, %2" : "=v"(r) : "v"(lo), "v"(hi));
  return r;
}
// tanh(x) = 1 - 2/(exp2(2*log2e*x)+1); saturates correctly, no clamp needed
__device__ __forceinline__ float tanh_fast(float x) {
  float e = __builtin_amdgcn_exp2f(x * 2.88539008177792681f);
  return fmaf(-2.f, __builtin_amdgcn_rcpf(e + 1.f), 1.f);
}

#define MFMA16(A, B, C) __builtin_amdgcn_mfma_f32_16x16x32_bf16((A), (B), (C), 0, 0, 0)

#define PACK_OUT(C, BV, DST) {                        \
  float t0_ = tanh_fast((C)[0] + (BV).x);             \
  float t1_ = tanh_fast((C)[1] + (BV).y);             \
  float t2_ = tanh_fast((C)[2] + (BV).z);             \
  float t3_ = tanh_fast((C)[3] + (BV).w);             \
  uint2 pk_; pk_.x = cvt_pk_bf16(t0_, t1_);           \
  pk_.y = cvt_pk_bf16(t2_, t3_);                      \
  *(uint2*)(DST) = pk_; }

extern "C" __global__ void __launch_bounds__(BLOCK, 1)
cstr_rk4_mfma5(const float* __restrict__ useq, const float* __restrict__ xGz0,
               const float* __restrict__ W1, const float* __restrict__ b1,
               const float* __restrict__ W2, const float* __restrict__ b2,
               const float* __restrict__ W3, const float* __restrict__ b3,
               float* __restrict__ out)
{
  extern __shared__ float smf[];
  unsigned* smu = (unsigned*)smf;
  unsigned short* smh = (unsigned short*)smf;

  unsigned short* w1h = smh + 2 * O_W1;   // [128][72]
  unsigned short* w2h = smh + 2 * O_W2;   // [128][136]
  unsigned short* w3h = smh + 2 * O_W3;   // [16][136]
  unsigned short* inh = smh + 2 * O_INB;  // [16][72]
  unsigned short* h1h = smh + 2 * O_H1;   // [16][136]
  unsigned short* h2h = smh + 2 * O_H2;
  unsigned* h1u = smu + O_H1;
  unsigned* h2u = smu + O_H2;
  float* b1s = smf + O_B1;
  float* b2s = smf + O_B2;
  float* b3s = smf + O_B3;
  float* su  = smf + O_SU;    // [4][256]
  float* ypm = smf + O_YPM;   // [4][40]
  float* upm = smf + O_UPM;   // [4][12]
  float* xm  = smf + O_XM;    // [4][8]

  const int tid  = threadIdx.x;
  const int w    = tid >> 6;     // wave 0..3
  const int l    = tid & 63;
  const int nn   = l & 15;       // frag col (batch row)
  const int hh   = l >> 4;       // k-quarter
  const int base = blockIdx.x * ROWS;

  // ================= one-time staging =================
  for (int i = tid; i < 128 * 72; i += BLOCK) {
    int j = i / 72, k = i % 72;
    w1h[i] = (k < 60) ? f2bf(W1[k * 128 + j]) : (unsigned short)0;
  }
  for (int i = tid; i < 128 * 136; i += BLOCK) {
    int j = i / 136, k = i % 136;
    w2h[i] = (k < 128) ? f2bf(W2[k * 128 + j]) : (unsigned short)0;
  }
  for (int i = tid; i < 16 * 136; i += BLOCK) {
    int o = i / 136, k = i % 136;
    w3h[i] = (o < 8 && k < 128) ? f2bf(W3[k * 8 + o]) : (unsigned short)0;
  }
  if (tid < 128) { b1s[tid] = b1[tid]; b2s[tid] = b2[tid]; }
  if (tid < 8) b3s[tid] = b3[tid];
  for (int i = tid; i < ROWS * 256; i += BLOCK) su[i] = useq[(size_t)base * 256 + i];
  for (int i = tid; i < ROWS * 40; i += BLOCK) {
    int r_ = i / 40, ci = i % 40;
    ypm[i] = xGz0[(size_t)(base + r_) * 58 + 8 + ci];
  }
  for (int i = tid; i < ROWS * 12; i += BLOCK) {
    int r_ = i / 12, ci = i % 12;
    upm[i] = (ci < 10) ? xGz0[(size_t)(base + r_) * 58 + 48 + ci] : 0.f;
  }
  for (int i = tid; i < ROWS * 8; i += BLOCK)
    xm[i] = xGz0[(size_t)(base + (i >> 3)) * 58 + (i & 7)];
  for (int i = tid; i < 16 * 72; i += BLOCK) {
    int n_ = i / 72, k = i % 72;
    unsigned short v = 0;
    if (n_ < ROWS) {
      if (k < 58)      v = f2bf(xGz0[(size_t)(base + n_) * 58 + k]);
      else if (k < 60) v = f2bf(useq[(size_t)(base + n_) * 256 + (k - 58)]);
    }
    inh[i] = v;
  }

  // state lanes: wave w owns batch row w; lanes 0..7 -> components
  const int sr = w;
  const int sc = l & 7;
  const bool st = (l < 8);
  float xg = 0.f, kacc = 0.f, b3r = 0.f;
  if (st) xg = xGz0[(size_t)(base + sr) * 58 + sc];

  __syncthreads();
  if (st) b3r = b3s[sc];

  // ====== loop-invariant weight fragments + biases -> registers ======
  const int mb0 = 2 * w, mb1 = 2 * w + 1;
  const s16x8 a10 = *(const s16x8*)(w1h + (16 * mb0 + nn) * 72 + 8 * hh);
  const s16x8 a11 = *(const s16x8*)(w1h + (16 * mb0 + nn) * 72 + 32 + 8 * hh);
  const s16x8 a12 = *(const s16x8*)(w1h + (16 * mb1 + nn) * 72 + 8 * hh);
  const s16x8 a13 = *(const s16x8*)(w1h + (16 * mb1 + nn) * 72 + 32 + 8 * hh);
  const s16x8 a200 = *(const s16x8*)(w2h + (16 * mb0 + nn) * 136 +  0 + 8 * hh);
  const s16x8 a201 = *(const s16x8*)(w2h + (16 * mb0 + nn) * 136 + 32 + 8 * hh);
  const s16x8 a202 = *(const s16x8*)(w2h + (16 * mb0 + nn) * 136 + 64 + 8 * hh);
  const s16x8 a203 = *(const s16x8*)(w2h + (16 * mb0 + nn) * 136 + 96 + 8 * hh);
  const s16x8 a210 = *(const s16x8*)(w2h + (16 * mb1 + nn) * 136 +  0 + 8 * hh);
  const s16x8 a211 = *(const s16x8*)(w2h + (16 * mb1 + nn) * 136 + 32 + 8 * hh);
  const s16x8 a212 = *(const s16x8*)(w2h + (16 * mb1 + nn) * 136 + 64 + 8 * hh);
  const s16x8 a213 = *(const s16x8*)(w2h + (16 * mb1 + nn) * 136 + 96 + 8 * hh);
  const s16x8 a30 = *(const s16x8*)(w3h + nn * 136 +  0 + 8 * hh);
  const s16x8 a31 = *(const s16x8*)(w3h + nn * 136 + 32 + 8 * hh);
  const s16x8 a32 = *(const s16x8*)(w3h + nn * 136 + 64 + 8 * hh);
  const s16x8 a33 = *(const s16x8*)(w3h + nn * 136 + 96 + 8 * hh);
  const float4 bva0 = *(const float4*)(b1s + 16 * mb0 + 4 * hh);
  const float4 bva1 = *(const float4*)(b1s + 16 * mb1 + 4 * hh);
  const float4 bvb0 = *(const float4*)(b2s + 16 * mb0 + 4 * hh);
  const float4 bvb1 = *(const float4*)(b2s + 16 * mb1 + 4 * hh);

  const unsigned short* inrow = inh + nn * 72;
  const unsigned short* h1row = h1h + nn * 136;
  const unsigned short* h2row = h2h + nn * 136;

  // shfl source lane for NN-output extraction: col sr=w, rows by (l>>2)&1
  const int srcl = (((l >> 2) & 1) << 4) + w;

  // ================= main loop =================
  #pragma unroll 1
  for (int t = 0; t < 128; ++t) {
    float u0r = 0.f, u1r = 0.f;
    if (st) {
      u0r = su[sr * 256 + 2 * t];
      u1r = su[sr * 256 + 2 * t + 1];
      out[((size_t)(base + sr) * 128 + t) * 8 + sc] = xg;   // y_t = xG
    }

    #pragma unroll
    for (int s = 0; s < 4; ++s) {
      // ---------- L1 (this wave's 32 neurons) ----------
      {
        s16x8 bb0 = *(const s16x8*)(inrow + 8 * hh);
        s16x8 bb1 = *(const s16x8*)(inrow + 32 + 8 * hh);
        f32x4 c1a = (f32x4){0.f, 0.f, 0.f, 0.f};
        f32x4 c1b = (f32x4){0.f, 0.f, 0.f, 0.f};
        c1a = MFMA16(a10, bb0, c1a); c1a = MFMA16(a11, bb1, c1a);
        c1b = MFMA16(a12, bb0, c1b); c1b = MFMA16(a13, bb1, c1b);
        PACK_OUT(c1a, bva0, h1u + nn * 68 + 8 * mb0 + 2 * hh);
        PACK_OUT(c1b, bva1, h1u + nn * 68 + 8 * mb1 + 2 * hh);
      }
      __syncthreads();

      // ---------- L2 (this wave's 32 neurons, full K=128) ----------
      {
        s16x8 q0 = *(const s16x8*)(h1row +  0 + 8 * hh);
        s16x8 q1 = *(const s16x8*)(h1row + 32 + 8 * hh);
        s16x8 q2 = *(const s16x8*)(h1row + 64 + 8 * hh);
        s16x8 q3 = *(const s16x8*)(h1row + 96 + 8 * hh);
        f32x4 c2a = (f32x4){0.f, 0.f, 0.f, 0.f};
        f32x4 c2b = (f32x4){0.f, 0.f, 0.f, 0.f};
        c2a = MFMA16(a200, q0, c2a); c2a = MFMA16(a201, q1, c2a);
        c2a = MFMA16(a202, q2, c2a); c2a = MFMA16(a203, q3, c2a);
        c2b = MFMA16(a210, q0, c2b); c2b = MFMA16(a211, q1, c2b);
        c2b = MFMA16(a212, q2, c2b); c2b = MFMA16(a213, q3, c2b);
        PACK_OUT(c2a, bvb0, h2u + nn * 68 + 8 * mb0 + 2 * hh);
        PACK_OUT(c2b, bvb1, h2u + nn * 68 + 8 * mb1 + 2 * hh);
      }
      __syncthreads();

      // ---------- L3 (redundant per wave, full K=128) + shfl extract ----------
      f32x4 c3 = (f32x4){0.f, 0.f, 0.f, 0.f};
      {
        s16x8 p0 = *(const s16x8*)(h2row +  0 + 8 * hh);
        s16x8 p1 = *(const s16x8*)(h2row + 32 + 8 * hh);
        s16x8 p2 = *(const s16x8*)(h2row + 64 + 8 * hh);
        s16x8 p3 = *(const s16x8*)(h2row + 96 + 8 * hh);
        c3 = MFMA16(a30, p0, c3); c3 = MFMA16(a31, p1, c3);
        c3 = MFMA16(a32, p2, c3); c3 = MFMA16(a33, p3, c3);
      }
      // lane srcl holds col w (batch row w), rows 4*((l>>2)&1)+i in c3[i]
      float v0 = __shfl(c3[0], srcl);
      float v1 = __shfl(c3[1], srcl);
      float v2 = __shfl(c3[2], srcl);
      float v3 = __shfl(c3[3], srcl);

      // ---------- state: kv = fg + nn; RK; z maintenance (wave-local row) ----------
      if (st) {
        float nv = b3r + ((sc & 2) ? ((sc & 1) ? v3 : v2)
                                   : ((sc & 1) ? v1 : v0));
        float4 xa = *(const float4*)(xm + sr * 8);
        float4 xb = *(const float4*)(xm + sr * 8 + 4);
        float Hr  = fmaf(xa.x, 2.f, 50.f),  CAr = fmaf(xa.y, 0.2f, 1.f);
        float CBr = fmaf(xa.z, 0.1f, 0.5f), Tr  = fmaf(xa.w, 4.f, 313.f);
        float Hb  = fmaf(xb.x, 2.f, 50.f),  CAb = fmaf(xb.y, 0.2f, 1.f);
        float CBb = fmaf(xb.z, 0.1f, 0.5f), Tb  = fmaf(xb.w, 4.f, 313.f);
        float F = u0r + 10.f, D = fmaf(u1r, 0.5f, 5.f);
        float Fr = 2.5f * sqrtf(Hr), Fb = 1.5f * sqrtf(Hb);
        float rH = __builtin_amdgcn_rcpf(3.f * Hr);
        float rB = __builtin_amdgcn_rcpf(3.f * Hb);
        float k0 = (F + D - Fr) * (1.f / 6.f);
        float k1 = (F * (6.f - CAr) - D * CAr) * (5.f * rH);
        float k2 = (-(F + D) * CBr) * (10.f * rH);
        float k3 = (F * (320.f - Tr) + D * (300.f - Tr)) * (0.25f * rH) + (5.f / 3.f) * rH;
        float k4 = (Fr - Fb - D) * (1.f / 6.f);
        float k5 = (Fr * (CAr - CAb) + D * CAb) * (5.f * rB);
        float k6 = (Fr * (CBr - CBb) + D * CBb) * (10.f * rB);
        float k7 = Fr * (Tr - Tb) * (0.25f * rB) + (5.f / 3.f) * rB;
        float fgc = (sc & 4) ? ((sc & 2) ? ((sc & 1) ? k7 : k6) : ((sc & 1) ? k5 : k4))
                             : ((sc & 2) ? ((sc & 1) ? k3 : k2) : ((sc & 1) ? k1 : k0));
        float kv = fgc + nv;
        float cc;
        if (s == 0)      { kacc = kv;                  cc = fmaf(kv, 0.005f, xg); }
        else if (s == 1) { kacc = fmaf(kv, 2.f, kacc); cc = fmaf(kv, 0.005f, xg); }
        else if (s == 2) { kacc = fmaf(kv, 2.f, kacc); cc = fmaf(kv, 0.01f,  xg); }
        else             { xg = fmaf(kacc + kv, 0.01f / 6.f, xg); cc = xg; }
        inh[sr * 72 + sc] = f2bf(cc);
        xm[sr * 8 + sc] = cc;

        if (s == 0) {            // yp_interp for k2/k3
          float a0 = ypm[sr * 40 + sc],      a1 = ypm[sr * 40 + 8 + sc];
          float a2 = ypm[sr * 40 + 16 + sc], a3 = ypm[sr * 40 + 24 + sc];
          float a4 = ypm[sr * 40 + 32 + sc], a5 = xg;
          inh[sr * 72 + 8 + sc]  = f2bf(0.5f * (a0 + a1));
          inh[sr * 72 + 16 + sc] = f2bf(0.5f * (a1 + a2));
          inh[sr * 72 + 24 + sc] = f2bf(0.5f * (a2 + a3));
          inh[sr * 72 + 32 + sc] = f2bf(0.5f * (a3 + a4));
          inh[sr * 72 + 40 + sc] = f2bf(0.5f * (a4 + a5));
        } else if (s == 2) {     // yp_shift for k4 + rotate ypm
          float a1 = ypm[sr * 40 + 8 + sc],  a2 = ypm[sr * 40 + 16 + sc];
          float a3 = ypm[sr * 40 + 24 + sc], a4 = ypm[sr * 40 + 32 + sc];
          float a5 = xg;
          inh[sr * 72 + 8 + sc]  = f2bf(a1);
          inh[sr * 72 + 16 + sc] = f2bf(a2);
          inh[sr * 72 + 24 + sc] = f2bf(a3);
          inh[sr * 72 + 32 + sc] = f2bf(a4);
          inh[sr * 72 + 40 + sc] = f2bf(a5);
          ypm[sr * 40 + sc]      = a1;
          ypm[sr * 40 + 8 + sc]  = a2;
          ypm[sr * 40 + 16 + sc] = a3;
          ypm[sr * 40 + 24 + sc] = a4;
          ypm[sr * 40 + 32 + sc] = a5;
        } else if (s == 3) {     // upseq shift + next-step u
          float nu = upm[sr * 12 + sc + 2];
          upm[sr * 12 + sc] = nu;
          inh[sr * 72 + 48 + sc] = f2bf(nu);
          if (sc < 2) {
            float uv = (sc == 0) ? u0r : u1r;
            upm[sr * 12 + 8 + sc] = uv;
            inh[sr * 72 + 56 + sc] = f2bf(uv);
            if (t < 127)
              inh[sr * 72 + 58 + sc] = f2bf(su[sr * 256 + 2 * (t + 1) + sc]);
          }
        }
      }
      __syncthreads();
    } // s
  } // t
}

extern "C" void kernel_launch(void* const* d_in, const int* in_sizes, int n_in,
                              void* d_out, int out_size, void* d_ws, size_t ws_size,
                              hipStream_t stream) {
  const float* useq = (const float*)d_in[0];
  const float* xGz0 = (const float*)d_in[1];
  const float* W1   = (const float*)d_in[2];
  const float* b1   = (const float*)d_in[3];
  const float* W2   = (const float*)d_in[4];
  const float* b2   = (const float*)d_in[5];
  const float* W3   = (const float*)d_in[6];
  const float* b3   = (const float*)d_in[7];
  float* out = (float*)d_out;

  size_t lds = (size_t)LDSN * sizeof(float);
  (void)hipFuncSetAttribute((const void*)cstr_rk4_mfma5,
                            hipFuncAttributeMaxDynamicSharedMemorySize, (int)lds);
  hipLaunchKernelGGL(cstr_rk4_mfma5, dim3(2048 / ROWS), dim3(BLOCK), lds, stream,
                     useq, xGz0, W1, b1, W2, b2, W3, b3, out);
}

// Round 6
// 541.555 us; speedup vs baseline: 1.3860x; 1.3860x over previous
//
#include <hip/hip_runtime.h>
#include <math.h>

#define BLOCK 512
#define ROWS 8

typedef __attribute__((ext_vector_type(8))) short s16x8;
typedef __attribute__((ext_vector_type(4))) float f32x4;

// ---- LDS layout (dword offsets) ----
static constexpr int O_H1   = 0;      // bf16 [16][136] = 1088 dw (shared)
static constexpr int O_H2   = 1088;   // bf16 [16][136] = 1088 dw (shared)
static constexpr int O_SU   = 2176;   // f32 [8][256]   = 2048 dw (shared, RO)
static constexpr int O_PRIV = 4224;   // per-wave: inhp bf16[16][72]=576dw + xmp f32[64]
static constexpr int PRIV_DW = 640;
static constexpr int LDSN  = O_PRIV + 8 * PRIV_DW;   // 9344 dw = 37376 B

__device__ __forceinline__ unsigned short f2bf(float f) {  // fp32->bf16 RNE
  unsigned u = __float_as_uint(f);
  return (unsigned short)((u + 0x7fffu + ((u >> 16) & 1u)) >> 16);
}
__device__ __forceinline__ unsigned cvt_pk_bf16(float lo, float hi) {
  unsigned r;
  asm("v_cvt_pk_bf16_f32 %0, %1, %2" : "=v"(r) : "v"(lo), "v"(hi));
  return r;
}
// tanh(x) = 1 - 2/(exp2(2*log2e*x)+1); saturates correctly, no clamp needed
__device__ __forceinline__ float tanh_fast(float x) {
  float e = __builtin_amdgcn_exp2f(x * 2.88539008177792681f);
  return fmaf(-2.f, __builtin_amdgcn_rcpf(e + 1.f), 1.f);
}

#define MFMA16(A, B, C) __builtin_amdgcn_mfma_f32_16x16x32_bf16((A), (B), (C), 0, 0, 0)

#define PACK_OUT(C, BV, DST) {                        \
  float t0_ = tanh_fast((C)[0] + (BV).x);             \
  float t1_ = tanh_fast((C)[1] + (BV).y);             \
  float t2_ = tanh_fast((C)[2] + (BV).z);             \
  float t3_ = tanh_fast((C)[3] + (BV).w);             \
  uint2 pk_; pk_.x = cvt_pk_bf16(t0_, t1_);           \
  pk_.y = cvt_pk_bf16(t2_, t3_);                      \
  *(uint2*)(DST) = pk_; }

extern "C" __global__ void __launch_bounds__(BLOCK, 1)
cstr_rk4_mfma6(const float* __restrict__ useq, const float* __restrict__ xGz0,
               const float* __restrict__ W1, const float* __restrict__ b1,
               const float* __restrict__ W2, const float* __restrict__ b2,
               const float* __restrict__ W3, const float* __restrict__ b3,
               float* __restrict__ out)
{
  extern __shared__ float smf[];
  unsigned short* h1h = (unsigned short*)(smf + O_H1);
  unsigned*       h1u = (unsigned*)(smf + O_H1);
  unsigned short* h2h = (unsigned short*)(smf + O_H2);
  unsigned*       h2u = (unsigned*)(smf + O_H2);
  float* su = smf + O_SU;   // [8][256]

  const int tid  = threadIdx.x;
  const int w    = tid >> 6;     // wave 0..7  (owns m-block w, batch handled jointly)
  const int l    = tid & 63;
  const int nn   = l & 15;       // frag col (batch row)
  const int hh   = l >> 4;       // k-quarter
  const int r    = l >> 3;       // state row  (0..7)
  const int c    = l & 7;        // state comp (0..7)
  const int base = blockIdx.x * ROWS;

  float* wp_ = smf + O_PRIV + w * PRIV_DW;
  unsigned short* inhp = (unsigned short*)wp_;   // private [16][72] bf16
  float* xmp = wp_ + 576;                        // private [8][8] f32

  // ---------- staging ----------
  for (int i = tid; i < ROWS * 256; i += BLOCK) su[i] = useq[(size_t)base * 256 + i];
  for (int i = l; i < 16 * 72; i += 64) {        // each wave stages its own copy
    int n_ = i / 72, k = i % 72;
    unsigned short v = 0;
    if (n_ < ROWS) {
      if (k < 58)      v = f2bf(xGz0[(size_t)(base + n_) * 58 + k]);
      else if (k < 60) v = f2bf(useq[(size_t)(base + n_) * 256 + (k - 58)]);
    }
    inhp[i] = v;
  }
  xmp[l] = xGz0[(size_t)(base + r) * 58 + c];

  // ---------- per-lane state registers (row r, comp c; replicated per wave) ----------
  const size_t rowb = (size_t)(base + r) * 58;
  float xg  = xGz0[rowb + c];
  float yp0 = xGz0[rowb + 8 + c],  yp1 = xGz0[rowb + 16 + c];
  float yp2 = xGz0[rowb + 24 + c], yp3 = xGz0[rowb + 32 + c];
  float yp4 = xGz0[rowb + 40 + c];
  float upA = xGz0[rowb + 48 + c];
  float upB = (c < 2) ? xGz0[rowb + 56 + c] : 0.f;
  float b3r = b3[c];
  float kacc = 0.f;

  // ---------- weights -> VGPR fragments (direct from global, one-time) ----------
  const int j = 16 * w + nn;
  s16x8 a10, a11, a20, a21, a22, a23, a30, a31, a32, a33;
  #pragma unroll
  for (int i = 0; i < 8; ++i) {
    int k0 = 8 * hh + i, k1 = 32 + 8 * hh + i;
    a10[i] = (short)f2bf(W1[k0 * 128 + j]);
    a11[i] = (short)((k1 < 60) ? f2bf(W1[k1 * 128 + j]) : 0);
    a20[i] = (short)f2bf(W2[(     8 * hh + i) * 128 + j]);
    a21[i] = (short)f2bf(W2[(32 + 8 * hh + i) * 128 + j]);
    a22[i] = (short)f2bf(W2[(64 + 8 * hh + i) * 128 + j]);
    a23[i] = (short)f2bf(W2[(96 + 8 * hh + i) * 128 + j]);
    unsigned short z0 = 0, z1 = 0, z2 = 0, z3 = 0;
    if (nn < 8) {
      z0 = f2bf(W3[(     8 * hh + i) * 8 + nn]);
      z1 = f2bf(W3[(32 + 8 * hh + i) * 8 + nn]);
      z2 = f2bf(W3[(64 + 8 * hh + i) * 8 + nn]);
      z3 = f2bf(W3[(96 + 8 * hh + i) * 8 + nn]);
    }
    a30[i] = (short)z0; a31[i] = (short)z1; a32[i] = (short)z2; a33[i] = (short)z3;
  }
  const float4 bva = *(const float4*)(b1 + 16 * w + 4 * hh);
  const float4 bvb = *(const float4*)(b2 + 16 * w + 4 * hh);

  __syncthreads();

  const int srcl = ((c >> 2) << 4) + r;   // shfl source for NN-output extract

  // ================= main loop =================
  #pragma unroll 1
  for (int t = 0; t < 128; ++t) {
    const float u0r = su[r * 256 + 2 * t];
    const float u1r = su[r * 256 + 2 * t + 1];
    if (w == 0) out[((size_t)(base + r) * 128 + t) * 8 + c] = xg;   // y_t = xG

    #pragma unroll
    for (int s = 0; s < 4; ++s) {
      // ---------- A: L1, m-block w (private inh, no barrier needed before) ----------
      {
        s16x8 bb0 = *(const s16x8*)(inhp + nn * 72 + 8 * hh);
        s16x8 bb1 = *(const s16x8*)(inhp + nn * 72 + 32 + 8 * hh);
        f32x4 c1 = (f32x4){0.f, 0.f, 0.f, 0.f};
        c1 = MFMA16(a10, bb0, c1);
        c1 = MFMA16(a11, bb1, c1);
        PACK_OUT(c1, bva, h1u + nn * 68 + 8 * w + 2 * hh);
      }
      __syncthreads();   // h1 complete

      // ---------- B: L2, m-block w (needs all h1) ----------
      {
        const unsigned short* h1row = h1h + nn * 136;
        s16x8 q0 = *(const s16x8*)(h1row +  0 + 8 * hh);
        s16x8 q1 = *(const s16x8*)(h1row + 32 + 8 * hh);
        s16x8 q2 = *(const s16x8*)(h1row + 64 + 8 * hh);
        s16x8 q3 = *(const s16x8*)(h1row + 96 + 8 * hh);
        f32x4 c2 = (f32x4){0.f, 0.f, 0.f, 0.f};
        c2 = MFMA16(a20, q0, c2); c2 = MFMA16(a21, q1, c2);
        c2 = MFMA16(a22, q2, c2); c2 = MFMA16(a23, q3, c2);
        PACK_OUT(c2, bvb, h2u + nn * 68 + 8 * w + 2 * hh);
      }
      __syncthreads();   // h2 complete

      // ---------- C: L3 (redundant, full K) + shfl + fg + RK + z (all lanes) ----------
      f32x4 c3 = (f32x4){0.f, 0.f, 0.f, 0.f};
      {
        const unsigned short* h2row = h2h + nn * 136;
        s16x8 p0 = *(const s16x8*)(h2row +  0 + 8 * hh);
        s16x8 p1 = *(const s16x8*)(h2row + 32 + 8 * hh);
        s16x8 p2 = *(const s16x8*)(h2row + 64 + 8 * hh);
        s16x8 p3 = *(const s16x8*)(h2row + 96 + 8 * hh);
        c3 = MFMA16(a30, p0, c3); c3 = MFMA16(a31, p1, c3);
        c3 = MFMA16(a32, p2, c3); c3 = MFMA16(a33, p3, c3);
      }
      float v0 = __shfl(c3[0], srcl);
      float v1 = __shfl(c3[1], srcl);
      float v2 = __shfl(c3[2], srcl);
      float v3 = __shfl(c3[3], srcl);
      {
        float nv = b3r + ((c & 2) ? ((c & 1) ? v3 : v2)
                                  : ((c & 1) ? v1 : v0));
        float4 xa = *(const float4*)(xmp + r * 8);
        float4 xb = *(const float4*)(xmp + r * 8 + 4);
        float Hr  = fmaf(xa.x, 2.f, 50.f),  CAr = fmaf(xa.y, 0.2f, 1.f);
        float CBr = fmaf(xa.z, 0.1f, 0.5f), Tr  = fmaf(xa.w, 4.f, 313.f);
        float Hb  = fmaf(xb.x, 2.f, 50.f),  CAb = fmaf(xb.y, 0.2f, 1.f);
        float CBb = fmaf(xb.z, 0.1f, 0.5f), Tb  = fmaf(xb.w, 4.f, 313.f);
        float F = u0r + 10.f, D = fmaf(u1r, 0.5f, 5.f);
        float Fr = 2.5f * sqrtf(Hr), Fb = 1.5f * sqrtf(Hb);
        float rH = __builtin_amdgcn_rcpf(3.f * Hr);
        float rB = __builtin_amdgcn_rcpf(3.f * Hb);
        float k0 = (F + D - Fr) * (1.f / 6.f);
        float k1 = (F * (6.f - CAr) - D * CAr) * (5.f * rH);
        float k2 = (-(F + D) * CBr) * (10.f * rH);
        float k3 = (F * (320.f - Tr) + D * (300.f - Tr)) * (0.25f * rH) + (5.f / 3.f) * rH;
        float k4 = (Fr - Fb - D) * (1.f / 6.f);
        float k5 = (Fr * (CAr - CAb) + D * CAb) * (5.f * rB);
        float k6 = (Fr * (CBr - CBb) + D * CBb) * (10.f * rB);
        float k7 = Fr * (Tr - Tb) * (0.25f * rB) + (5.f / 3.f) * rB;
        float fgc = (c & 4) ? ((c & 2) ? ((c & 1) ? k7 : k6) : ((c & 1) ? k5 : k4))
                            : ((c & 2) ? ((c & 1) ? k3 : k2) : ((c & 1) ? k1 : k0));
        float kv = fgc + nv;
        float cc;
        if (s == 0)      { kacc = kv;                  cc = fmaf(kv, 0.005f, xg); }
        else if (s == 1) { kacc = fmaf(kv, 2.f, kacc); cc = fmaf(kv, 0.005f, xg); }
        else if (s == 2) { kacc = fmaf(kv, 2.f, kacc); cc = fmaf(kv, 0.01f,  xg); }
        else             { xg = fmaf(kacc + kv, 0.01f / 6.f, xg); cc = xg; }
        xmp[r * 8 + c] = cc;                 // next stage's fg input (private)
        inhp[r * 72 + c] = f2bf(cc);         // next stage's L1 input (private)

        if (s == 0) {            // yp_interp for k2/k3
          inhp[r * 72 +  8 + c] = f2bf(0.5f * (yp0 + yp1));
          inhp[r * 72 + 16 + c] = f2bf(0.5f * (yp1 + yp2));
          inhp[r * 72 + 24 + c] = f2bf(0.5f * (yp2 + yp3));
          inhp[r * 72 + 32 + c] = f2bf(0.5f * (yp3 + yp4));
          inhp[r * 72 + 40 + c] = f2bf(0.5f * (yp4 + xg));
        } else if (s == 2) {     // yp_shift for k4 + rotate (next ypseq)
          inhp[r * 72 +  8 + c] = f2bf(yp1);
          inhp[r * 72 + 16 + c] = f2bf(yp2);
          inhp[r * 72 + 24 + c] = f2bf(yp3);
          inhp[r * 72 + 32 + c] = f2bf(yp4);
          inhp[r * 72 + 40 + c] = f2bf(xg);
          yp0 = yp1; yp1 = yp2; yp2 = yp3; yp3 = yp4; yp4 = xg;
        } else if (s == 3) {     // upseq shift + next-step u
          float tA = __shfl(upA, r * 8 + ((c + 2) & 7));
          float tB = __shfl(upB, r * 8 + ((c >= 6) ? (c - 6) : 0));
          float nu = (c < 6) ? tA : tB;
          upA = nu;
          inhp[r * 72 + 48 + c] = f2bf(nu);
          if (c < 2) {
            float uv = (c == 0) ? u0r : u1r;
            upB = uv;
            inhp[r * 72 + 56 + c] = f2bf(uv);
            if (t < 127)
              inhp[r * 72 + 58 + c] = f2bf(su[r * 256 + 2 * (t + 1) + c]);
          }
        }
      }
    } // s
  } // t
}

extern "C" void kernel_launch(void* const* d_in, const int* in_sizes, int n_in,
                              void* d_out, int out_size, void* d_ws, size_t ws_size,
                              hipStream_t stream) {
  const float* useq = (const float*)d_in[0];
  const float* xGz0 = (const float*)d_in[1];
  const float* W1   = (const float*)d_in[2];
  const float* b1   = (const float*)d_in[3];
  const float* W2   = (const float*)d_in[4];
  const float* b2   = (const float*)d_in[5];
  const float* W3   = (const float*)d_in[6];
  const float* b3   = (const float*)d_in[7];
  float* out = (float*)d_out;

  size_t lds = (size_t)LDSN * sizeof(float);
  (void)hipFuncSetAttribute((const void*)cstr_rk4_mfma6,
                            hipFuncAttributeMaxDynamicSharedMemorySize, (int)lds);
  hipLaunchKernelGGL(cstr_rk4_mfma6, dim3(2048 / ROWS), dim3(BLOCK), lds, stream,
                     useq, xGz0, W1, b1, W2, b2, W3, b3, out);
}

// Round 7
// 477.997 us; speedup vs baseline: 1.5702x; 1.1330x over previous
//
#include <hip/hip_runtime.h>
#include <math.h>

#define BLOCK 512
#define ROWS 8

typedef __attribute__((ext_vector_type(8))) short s16x8;
typedef __attribute__((ext_vector_type(4))) float f32x4;

// ---- LDS layout (dword offsets) ----
static constexpr int O_H1  = 0;      // bf16 [16][136] = 1088 dw
static constexpr int O_H2  = 1088;   // bf16 [16][136] = 1088 dw
static constexpr int O_INH = 2176;   // bf16 [16][72]  = 576 dw (shared; written by wave 0)
static constexpr int O_XM  = 2752;   // f32 [8][8]     = 64 dw  (wave-0 state mirror)
static constexpr int O_SU  = 2816;   // f32 [8][260]   = 2080 dw (stride 260 kills bank alias)
static constexpr int LDSN  = 4896;   // 19584 bytes

__device__ __forceinline__ unsigned short f2bf(float f) {  // fp32->bf16 RNE
  unsigned u = __float_as_uint(f);
  return (unsigned short)((u + 0x7fffu + ((u >> 16) & 1u)) >> 16);
}
__device__ __forceinline__ unsigned cvt_pk_bf16(float lo, float hi) {
  unsigned r;
  asm("v_cvt_pk_bf16_f32 %0, %1, %2" : "=v"(r) : "v"(lo), "v"(hi));
  return r;
}
// tanh(x) = 1 - 2/(exp2(2*log2e*x)+1); saturates correctly at +/-inf
__device__ __forceinline__ float tanh_fast(float x) {
  float e = __builtin_amdgcn_exp2f(x * 2.88539008177792681f);
  return fmaf(-2.f, __builtin_amdgcn_rcpf(e + 1.f), 1.f);
}

#define MFMA16(A, B, C) __builtin_amdgcn_mfma_f32_16x16x32_bf16((A), (B), (C), 0, 0, 0)

#define PACK_OUT(C, BV, DST) {                        \
  float t0_ = tanh_fast((C)[0] + (BV).x);             \
  float t1_ = tanh_fast((C)[1] + (BV).y);             \
  float t2_ = tanh_fast((C)[2] + (BV).z);             \
  float t3_ = tanh_fast((C)[3] + (BV).w);             \
  uint2 pk_; pk_.x = cvt_pk_bf16(t0_, t1_);           \
  pk_.y = cvt_pk_bf16(t2_, t3_);                      \
  *(uint2*)(DST) = pk_; }

extern "C" __global__ void __launch_bounds__(BLOCK, 1)
cstr_rk4_mfma7(const float* __restrict__ useq, const float* __restrict__ xGz0,
               const float* __restrict__ W1, const float* __restrict__ b1,
               const float* __restrict__ W2, const float* __restrict__ b2,
               const float* __restrict__ W3, const float* __restrict__ b3,
               float* __restrict__ out)
{
  extern __shared__ float smf[];
  unsigned short* h1h = (unsigned short*)(smf + O_H1);
  unsigned*       h1u = (unsigned*)(smf + O_H1);
  unsigned short* h2h = (unsigned short*)(smf + O_H2);
  unsigned*       h2u = (unsigned*)(smf + O_H2);
  unsigned short* inh = (unsigned short*)(smf + O_INH);  // shared [16][72]
  float* xm = smf + O_XM;   // [8][8], wave-0 use only
  float* su = smf + O_SU;   // [8][260]

  const int tid  = threadIdx.x;
  const int w    = tid >> 6;     // wave 0..7 (owns m-block w)
  const int l    = tid & 63;
  const int nn   = l & 15;       // frag col (batch row)
  const int hh   = l >> 4;       // k-quarter
  const int r    = l >> 3;       // state row  (0..7)
  const int c    = l & 7;        // state comp (0..7)
  const int base = blockIdx.x * ROWS;

  // ---------- staging (block-wide, single shared copies) ----------
  for (int i = tid; i < 8 * 260; i += BLOCK) {
    int row = i / 260, col = i % 260;
    su[i] = (col < 256) ? useq[(size_t)base * 256 + row * 256 + col] : 0.f;
  }
  for (int i = tid; i < 16 * 72; i += BLOCK) {
    int n_ = i / 72, k = i % 72;
    unsigned short v = 0;
    if (n_ < ROWS) {
      if (k < 58)      v = f2bf(xGz0[(size_t)(base + n_) * 58 + k]);
      else if (k < 60) v = f2bf(useq[(size_t)(base + n_) * 256 + (k - 58)]);
    }
    inh[i] = v;
  }
  if (tid < 64) xm[tid] = xGz0[(size_t)(base + (tid >> 3)) * 58 + (tid & 7)];

  // ---------- per-lane state registers (meaningful on wave 0 only) ----------
  const size_t rowb = (size_t)(base + r) * 58;
  float xg  = xGz0[rowb + c];
  float yp0 = xGz0[rowb + 8 + c],  yp1 = xGz0[rowb + 16 + c];
  float yp2 = xGz0[rowb + 24 + c], yp3 = xGz0[rowb + 32 + c];
  float yp4 = xGz0[rowb + 40 + c];
  float upA = xGz0[rowb + 48 + c];
  float upB = (c < 2) ? xGz0[rowb + 56 + c] : 0.f;
  float b3r = b3[c];
  float kacc = 0.f;

  // ---------- weights -> VGPR fragments (direct from global, one-time) ----------
  const int j = 16 * w + nn;
  s16x8 a10, a11, a20, a21, a22, a23, a30, a31, a32, a33;
  #pragma unroll
  for (int i = 0; i < 8; ++i) {
    int k0 = 8 * hh + i, k1 = 32 + 8 * hh + i;
    a10[i] = (short)f2bf(W1[k0 * 128 + j]);
    a11[i] = (short)((k1 < 60) ? f2bf(W1[k1 * 128 + j]) : 0);
    a20[i] = (short)f2bf(W2[(     8 * hh + i) * 128 + j]);
    a21[i] = (short)f2bf(W2[(32 + 8 * hh + i) * 128 + j]);
    a22[i] = (short)f2bf(W2[(64 + 8 * hh + i) * 128 + j]);
    a23[i] = (short)f2bf(W2[(96 + 8 * hh + i) * 128 + j]);
    unsigned short z0 = 0, z1 = 0, z2 = 0, z3 = 0;
    if (nn < 8) {
      z0 = f2bf(W3[(     8 * hh + i) * 8 + nn]);
      z1 = f2bf(W3[(32 + 8 * hh + i) * 8 + nn]);
      z2 = f2bf(W3[(64 + 8 * hh + i) * 8 + nn]);
      z3 = f2bf(W3[(96 + 8 * hh + i) * 8 + nn]);
    }
    a30[i] = (short)z0; a31[i] = (short)z1; a32[i] = (short)z2; a33[i] = (short)z3;
  }
  const float4 bva = *(const float4*)(b1 + 16 * w + 4 * hh);
  const float4 bvb = *(const float4*)(b2 + 16 * w + 4 * hh);

  __syncthreads();

  const int srcl = ((c >> 2) << 4) + r;   // shfl source for NN-output extract

  // ================= main loop =================
  #pragma unroll 1
  for (int t = 0; t < 128; ++t) {
    float u0r = 0.f, u1r = 0.f;
    if (w == 0) {
      u0r = su[r * 260 + 2 * t];
      u1r = su[r * 260 + 2 * t + 1];
      out[((size_t)(base + r) * 128 + t) * 8 + c] = xg;   // y_t = xG
    }

    #pragma unroll
    for (int s = 0; s < 4; ++s) {
      // ---------- A: L1, m-block w (reads shared inh) ----------
      {
        s16x8 bb0 = *(const s16x8*)(inh + nn * 72 + 8 * hh);
        s16x8 bb1 = *(const s16x8*)(inh + nn * 72 + 32 + 8 * hh);
        f32x4 c1 = (f32x4){0.f, 0.f, 0.f, 0.f};
        c1 = MFMA16(a10, bb0, c1);
        c1 = MFMA16(a11, bb1, c1);
        PACK_OUT(c1, bva, h1u + nn * 68 + 8 * w + 2 * hh);
      }
      __syncthreads();   // h1 complete

      // ---------- B: L2, m-block w (needs all h1) ----------
      {
        const unsigned short* h1row = h1h + nn * 136;
        s16x8 q0 = *(const s16x8*)(h1row +  0 + 8 * hh);
        s16x8 q1 = *(const s16x8*)(h1row + 32 + 8 * hh);
        s16x8 q2 = *(const s16x8*)(h1row + 64 + 8 * hh);
        s16x8 q3 = *(const s16x8*)(h1row + 96 + 8 * hh);
        f32x4 c2 = (f32x4){0.f, 0.f, 0.f, 0.f};
        c2 = MFMA16(a20, q0, c2); c2 = MFMA16(a21, q1, c2);
        c2 = MFMA16(a22, q2, c2); c2 = MFMA16(a23, q3, c2);
        PACK_OUT(c2, bvb, h2u + nn * 68 + 8 * w + 2 * hh);
      }
      __syncthreads();   // h2 complete

      // ---------- C: wave 0 ONLY — L3 + fg + RK + z maintenance ----------
      if (w == 0) {
        f32x4 c3 = (f32x4){0.f, 0.f, 0.f, 0.f};
        {
          const unsigned short* h2row = h2h + nn * 136;
          s16x8 p0 = *(const s16x8*)(h2row +  0 + 8 * hh);
          s16x8 p1 = *(const s16x8*)(h2row + 32 + 8 * hh);
          s16x8 p2 = *(const s16x8*)(h2row + 64 + 8 * hh);
          s16x8 p3 = *(const s16x8*)(h2row + 96 + 8 * hh);
          c3 = MFMA16(a30, p0, c3); c3 = MFMA16(a31, p1, c3);
          c3 = MFMA16(a32, p2, c3); c3 = MFMA16(a33, p3, c3);
        }
        float v0 = __shfl(c3[0], srcl);
        float v1 = __shfl(c3[1], srcl);
        float v2 = __shfl(c3[2], srcl);
        float v3 = __shfl(c3[3], srcl);

        float nv = b3r + ((c & 2) ? ((c & 1) ? v3 : v2)
                                  : ((c & 1) ? v1 : v0));
        float4 xa = *(const float4*)(xm + r * 8);
        float4 xb = *(const float4*)(xm + r * 8 + 4);
        float Hr  = fmaf(xa.x, 2.f, 50.f),  CAr = fmaf(xa.y, 0.2f, 1.f);
        float CBr = fmaf(xa.z, 0.1f, 0.5f), Tr  = fmaf(xa.w, 4.f, 313.f);
        float Hb  = fmaf(xb.x, 2.f, 50.f),  CAb = fmaf(xb.y, 0.2f, 1.f);
        float CBb = fmaf(xb.z, 0.1f, 0.5f), Tb  = fmaf(xb.w, 4.f, 313.f);
        float F = u0r + 10.f, D = fmaf(u1r, 0.5f, 5.f);
        float Fr = 2.5f * sqrtf(Hr), Fb = 1.5f * sqrtf(Hb);
        float rH = __builtin_amdgcn_rcpf(3.f * Hr);
        float rB = __builtin_amdgcn_rcpf(3.f * Hb);
        float k0 = (F + D - Fr) * (1.f / 6.f);
        float k1 = (F * (6.f - CAr) - D * CAr) * (5.f * rH);
        float k2 = (-(F + D) * CBr) * (10.f * rH);
        float k3 = (F * (320.f - Tr) + D * (300.f - Tr)) * (0.25f * rH) + (5.f / 3.f) * rH;
        float k4 = (Fr - Fb - D) * (1.f / 6.f);
        float k5 = (Fr * (CAr - CAb) + D * CAb) * (5.f * rB);
        float k6 = (Fr * (CBr - CBb) + D * CBb) * (10.f * rB);
        float k7 = Fr * (Tr - Tb) * (0.25f * rB) + (5.f / 3.f) * rB;
        float fgc = (c & 4) ? ((c & 2) ? ((c & 1) ? k7 : k6) : ((c & 1) ? k5 : k4))
                            : ((c & 2) ? ((c & 1) ? k3 : k2) : ((c & 1) ? k1 : k0));
        float kv = fgc + nv;
        float cc;
        if (s == 0)      { kacc = kv;                  cc = fmaf(kv, 0.005f, xg); }
        else if (s == 1) { kacc = fmaf(kv, 2.f, kacc); cc = fmaf(kv, 0.005f, xg); }
        else if (s == 2) { kacc = fmaf(kv, 2.f, kacc); cc = fmaf(kv, 0.01f,  xg); }
        else             { xg = fmaf(kacc + kv, 0.01f / 6.f, xg); cc = xg; }
        xm[r * 8 + c] = cc;                 // next stage's fg input
        inh[r * 72 + c] = f2bf(cc);         // next stage's L1 input

        if (s == 0) {            // yp_interp for k2/k3
          inh[r * 72 +  8 + c] = f2bf(0.5f * (yp0 + yp1));
          inh[r * 72 + 16 + c] = f2bf(0.5f * (yp1 + yp2));
          inh[r * 72 + 24 + c] = f2bf(0.5f * (yp2 + yp3));
          inh[r * 72 + 32 + c] = f2bf(0.5f * (yp3 + yp4));
          inh[r * 72 + 40 + c] = f2bf(0.5f * (yp4 + xg));
        } else if (s == 2) {     // yp_shift for k4 + rotate (next ypseq)
          inh[r * 72 +  8 + c] = f2bf(yp1);
          inh[r * 72 + 16 + c] = f2bf(yp2);
          inh[r * 72 + 24 + c] = f2bf(yp3);
          inh[r * 72 + 32 + c] = f2bf(yp4);
          inh[r * 72 + 40 + c] = f2bf(xg);
          yp0 = yp1; yp1 = yp2; yp2 = yp3; yp3 = yp4; yp4 = xg;
        } else if (s == 3) {     // upseq shift + next-step u
          float tA = __shfl(upA, r * 8 + ((c + 2) & 7));
          float tB = __shfl(upB, r * 8 + ((c >= 6) ? (c - 6) : 0));
          float nu = (c < 6) ? tA : tB;
          upA = nu;
          inh[r * 72 + 48 + c] = f2bf(nu);
          if (c < 2) {
            float uv = (c == 0) ? u0r : u1r;
            upB = uv;
            inh[r * 72 + 56 + c] = f2bf(uv);
            if (t < 127)
              inh[r * 72 + 58 + c] = f2bf(su[r * 260 + 2 * (t + 1) + c]);
          }
        }
      }
      __syncthreads();   // state/inh published
    } // s
  } // t
}

extern "C" void kernel_launch(void* const* d_in, const int* in_sizes, int n_in,
                              void* d_out, int out_size, void* d_ws, size_t ws_size,
                              hipStream_t stream) {
  const float* useq = (const float*)d_in[0];
  const float* xGz0 = (const float*)d_in[1];
  const float* W1   = (const float*)d_in[2];
  const float* b1   = (const float*)d_in[3];
  const float* W2   = (const float*)d_in[4];
  const float* b2   = (const float*)d_in[5];
  const float* W3   = (const float*)d_in[6];
  const float* b3   = (const float*)d_in[7];
  float* out = (float*)d_out;

  size_t lds = (size_t)LDSN * sizeof(float);
  (void)hipFuncSetAttribute((const void*)cstr_rk4_mfma7,
                            hipFuncAttributeMaxDynamicSharedMemorySize, (int)lds);
  hipLaunchKernelGGL(cstr_rk4_mfma7, dim3(2048 / ROWS), dim3(BLOCK), lds, stream,
                     useq, xGz0, W1, b1, W2, b2, W3, b3, out);
}